// Round 14
// baseline (477.677 us; speedup 1.0000x reference)
//
#include <hip/hip_runtime.h>

// HierarchicalRNN T=32,B=16,I=128,H=384,O=32.
// Round-14: BARRIER-FREE all-wave polling (round-2 dataflow + round-6 poll).
//   256 blocks x 512 threads, (512,2). Each wave owns 3 rows; each wave
//   polls its own 6 lane-words of noc[t]/noh[t] with branch-free parallel
//   issue; poll loads are issued right after publish and checked after the
//   hidden work (prefetch/out/plast) -> plast runs under the poll flight.
//   No __syncthreads, no LDS, no poller relay: detection ~1 MALL RTT after
//   the last producer's publish.
// Agent-scope relaxed atomics, self-flagging words (v+2.0, sentinel 0),
// t-indexed buffers (no reuse -> no WAR hazards).

#define NT 32
#define NBATCH 16
#define DI 128
#define DH 384
#define DOUT 32
#define CSZ (NT * NBATCH * DH)

__device__ __forceinline__ float retanh_f(float z) {
  z = fmaxf(z, 0.0f);
  float e = __expf(-2.0f * z);
  return (1.0f - e) / (1.0f + e);
}

__device__ __forceinline__ float aldf(const float* p) {
  return __hip_atomic_load(p, __ATOMIC_RELAXED, __HIP_MEMORY_SCOPE_AGENT);
}
__device__ __forceinline__ void pubG(float* p, float v) {
  __hip_atomic_store(p, v, __ATOMIC_RELAXED, __HIP_MEMORY_SCOPE_AGENT);
}

__global__ __launch_bounds__(512, 2) void hrnn(
    const float* __restrict__ x, const float* __restrict__ Rs,
    const float* __restrict__ Wx, const float* __restrict__ Wc, const float* __restrict__ bc,
    const float* __restrict__ Wch, const float* __restrict__ Whh, const float* __restrict__ bh,
    const float* __restrict__ Wo, const float* __restrict__ Wa, const float* __restrict__ ba,
    const float* __restrict__ kap, float* __restrict__ out, float* __restrict__ comm) {
  const int tid  = threadIdx.x;
  const int lane = tid & 63;
  const int wv   = tid >> 6;
  const int bid  = blockIdx.x;
  const int b = ((bid & 7) << 1) | ((bid >> 3) & 1);
  const int k = bid >> 4;

  float* noc_buf = comm;         // [NT][NBATCH][DH]
  float* noh_buf = comm + CSZ;   // [NT][NBATCH][DH]

  const int og0 = k * 24 + wv * 3;
  const bool do_out = (k == 15);

  // persistent plastic weights + cached relu(W_slow) slices (all registers)
  float wxc[3][2], wcc[3][6], wchv[3][5], whh[3][6];
  float rWx[3][2], rWc[3][6], rWch[3][5], rWhh[3][6], rWa[3][5];
  float sc[3], shs[3], bcr[3], bar3[3], bhr[3];
  float ohr[6], ocr[6];
  float rWo[4][5];
  float kp[12];

#pragma unroll
  for (int r = 0; r < 3; ++r) {
    const int og = og0 + r;
#pragma unroll
    for (int j = 0; j < 2; ++j) { rWx[r][j] = fmaxf(Wx[og*DI + j*64 + lane], 0.f); wxc[r][j] = 0.f; }
#pragma unroll
    for (int j = 0; j < 6; ++j) { rWc[r][j] = fmaxf(Wc[og*DH + j*64 + lane], 0.f); wcc[r][j] = 0.f; }
#pragma unroll
    for (int j = 0; j < 5; ++j) { rWch[r][j] = fmaxf(Wch[og*DH + j*64 + lane], 0.f); wchv[r][j] = 0.f; }
#pragma unroll
    for (int j = 0; j < 6; ++j) { rWhh[r][j] = fmaxf(Whh[og*DH + j*64 + lane], 0.f); whh[r][j] = 0.f; }
#pragma unroll
    for (int j = 0; j < 5; ++j) {
      float w = fmaxf(Wa[og*DH + j*64 + lane], 0.f);
      rWa[r][j] = (j == 4 && lane >= 51) ? 0.f : w;   // attn mask: cols>=307 zero
    }
    sc[r] = 0.f; shs[r] = 0.f;
    bcr[r] = bc[og]; bar3[r] = ba[og]; bhr[r] = bh[og];
  }
  if (do_out) {
#pragma unroll
    for (int m = 0; m < 4; ++m) {
      const int o = wv * 4 + m;
#pragma unroll
      for (int j = 0; j < 5; ++j) {
        float w = fmaxf(Wo[o*DH + j*64 + lane], 0.f);
        rWo[m][j] = (j == 4 && lane >= 51) ? 0.f : w;  // h2o mask: cols>=307 zero
      }
    }
  }
#pragma unroll
  for (int j = 0; j < 6; ++j) { ohr[j] = 0.f; ocr[j] = 0.f; }
#pragma unroll
  for (int j = 0; j < 12; ++j) kp[j] = kap[j];

  // prefetch step-0 inputs
  float xp0 = x[b*DI + lane];
  float xp1 = x[b*DI + 64 + lane];
  float dtRp = 0.02f * Rs[b];

  for (int t = 0; t < NT; ++t) {
    const int toff = t * NBATCH * DH + b * DH;

    const float dtR = dtRp;
    const float x0 = xp0;
    const float x1 = xp1;
    // column sign masks (boundary col 307 = j4/lane51)
    const float oh4s = (lane < 51) ? ohr[4] : -ohr[4];
    const float oc4s = (lane < 51) ? ocr[4] : -ocr[4];
    const float inC[6] = { ocr[0], ocr[1], ocr[2], ocr[3], oc4s, -ocr[5] };

    // ---------------- phase A (cell layer) ----------------
    float nocr[3];
#pragma unroll
    for (int r = 0; r < 3; ++r) {
      const int og = og0 + r;
      const int dj = og >> 6, dl = og & 63;
      float accA = 0.f, accT = 0.f;
#pragma unroll
      for (int j = 0; j < 5; ++j) accA += rWa[r][j] * ohr[j];
      accT += (rWx[r][0] + wxc[r][0]) * x0;
      accT += (rWx[r][1] + wxc[r][1]) * x1;
#pragma unroll
      for (int j = 0; j < 6; ++j) {
        float term = (rWc[r][j] + wcc[r][j]) * inC[j];
        if (j == dj) term = (lane == dl) ? 0.f : term;  // remove_diag
        accT += term;
      }
#pragma unroll
      for (int mm = 1; mm <= 32; mm <<= 1) {
        accA += __shfl_xor(accA, mm, 64);
        accT += __shfl_xor(accT, mm, 64);
      }
      const float attn = retanh_f(accA + bar3[r]);
      const float tic = accT + bcr[r] + attn;
      sc[r] = 0.8f*sc[r] + 0.2f*tic;
      nocr[r] = retanh_f(sc[r]);
    }
    {  // coalesced publish: lanes 0..2, 12B per wave, ASAP
      float mine = (lane == 0) ? nocr[0] : (lane == 1) ? nocr[1] : nocr[2];
      if (lane < 3) pubG(noc_buf + toff + og0 + lane, mine + 2.0f);
    }

    // issue own noc[t] poll loads NOW (flight overlaps hidden work below)
    const float* ppc = noc_buf + toff + lane;
    float pc0 = aldf(ppc + 0*64), pc1 = aldf(ppc + 1*64), pc2 = aldf(ppc + 2*64);
    float pc3 = aldf(ppc + 3*64), pc4 = aldf(ppc + 4*64), pc5 = aldf(ppc + 5*64);

    // --- hidden work: prefetch, out[t-1], plast A ---
    if (t < NT-1) {
      xp0 = x[((t+1)*NBATCH + b)*DI + lane];
      xp1 = x[((t+1)*NBATCH + b)*DI + 64 + lane];
      dtRp = 0.02f * Rs[(t+1)*NBATCH + b];
    }
    if (do_out && t > 0) {
#pragma unroll
      for (int m = 0; m < 4; ++m) {
        float a = 0.f;
#pragma unroll
        for (int j = 0; j < 5; ++j) a += rWo[m][j] * ohr[j];
#pragma unroll
        for (int mm = 1; mm <= 32; mm <<= 1) a += __shfl_xor(a, mm, 64);
        if (lane == 0) out[(t-1)*NBATCH*DOUT + b*DOUT + wv*4 + m] = a;
      }
    }
    if (t < NT-1) {  // plast wxc, wcc (uses OLD oc)
      float axc[2], bxc[2];
#pragma unroll
      for (int j = 0; j < 2; ++j) {
        const float pre_ = (j == 0) ? x0 : x1;
        axc[j] = dtR*kp[0]*pre_; bxc[j] = dtR*(kp[1] + kp[2]*pre_);
      }
      float acc_[6], bcc_[6];
#pragma unroll
      for (int j = 0; j < 6; ++j) { acc_[j] = dtR*kp[3]*ocr[j]; bcc_[j] = dtR*(kp[4] + kp[5]*ocr[j]); }
#pragma unroll
      for (int r = 0; r < 3; ++r) {
        const float post = nocr[r];
#pragma unroll
        for (int j = 0; j < 2; ++j)
          wxc[r][j] = fmaxf(fmaf(wxc[r][j], 0.98f, fmaf(bxc[j], post, axc[j])), -rWx[r][j]);
#pragma unroll
        for (int j = 0; j < 6; ++j)
          wcc[r][j] = fmaxf(fmaf(wcc[r][j], 0.98f, fmaf(bcc_[j], post, acc_[j])), -rWc[r][j]);
      }
    }

    // finish own noc poll (branch-free re-issue rounds)
    for (;;) {
      const bool ok = (pc0 != 0.f) & (pc1 != 0.f) & (pc2 != 0.f) &
                      (pc3 != 0.f) & (pc4 != 0.f) & (pc5 != 0.f);
      if (ok) break;
      pc0 = aldf(ppc + 0*64); pc1 = aldf(ppc + 1*64); pc2 = aldf(ppc + 2*64);
      pc3 = aldf(ppc + 3*64); pc4 = aldf(ppc + 4*64); pc5 = aldf(ppc + 5*64);
    }
    float ncr[6];
    ncr[0] = pc0 - 2.f; ncr[1] = pc1 - 2.f; ncr[2] = pc2 - 2.f;
    ncr[3] = pc3 - 2.f; ncr[4] = pc4 - 2.f; ncr[5] = pc5 - 2.f;

    // ---------------- phase B (hidden layer) ----------------
    const float nc4z = (lane < 51) ? ncr[4] : 0.f;
    const float inH[6] = { ohr[0], ohr[1], ohr[2], ohr[3], oh4s, -ohr[5] };
    const float inN[5] = { ncr[0], ncr[1], ncr[2], ncr[3], nc4z };
    float nohr[3];
#pragma unroll
    for (int r = 0; r < 3; ++r) {
      const int og = og0 + r;
      const int dj = og >> 6, dl = og & 63;
      float acc = 0.f;
#pragma unroll
      for (int j = 0; j < 5; ++j) acc += (rWch[r][j] + wchv[r][j]) * inN[j];
#pragma unroll
      for (int j = 0; j < 6; ++j) {
        float term = (rWhh[r][j] + whh[r][j]) * inH[j];
        if (j == dj) term = (lane == dl) ? 0.f : term;
        acc += term;
      }
#pragma unroll
      for (int mm = 1; mm <= 32; mm <<= 1) acc += __shfl_xor(acc, mm, 64);
      const float tih = acc + bhr[r];
      shs[r] = 0.8f*shs[r] + 0.2f*tih;
      nohr[r] = retanh_f(shs[r]);
    }
    {  // publish ASAP
      float mine = (lane == 0) ? nohr[0] : (lane == 1) ? nohr[1] : nohr[2];
      if (lane < 3) pubG(noh_buf + toff + og0 + lane, mine + 2.0f);
    }

    // issue own noh[t] poll loads NOW (flight overlaps plast B)
    const float* pph = noh_buf + toff + lane;
    float ph0 = aldf(pph + 0*64), ph1 = aldf(pph + 1*64), ph2 = aldf(pph + 2*64);
    float ph3 = aldf(pph + 3*64), ph4 = aldf(pph + 4*64), ph5 = aldf(pph + 5*64);

    // --- hidden work: plast B (pre: new noc / old oh; post: new noh) ---
    if (t < NT-1) {
      float an_[5], bn_[5];
#pragma unroll
      for (int j = 0; j < 5; ++j) { an_[j] = dtR*kp[6]*ncr[j]; bn_[j] = dtR*(kp[7] + kp[8]*ncr[j]); }
      float ah_[6], bh_[6];
#pragma unroll
      for (int j = 0; j < 6; ++j) { ah_[j] = dtR*kp[9]*ohr[j]; bh_[j] = dtR*(kp[10] + kp[11]*ohr[j]); }
#pragma unroll
      for (int r = 0; r < 3; ++r) {
        const float post = nohr[r];
#pragma unroll
        for (int j = 0; j < 5; ++j)
          wchv[r][j] = fmaxf(fmaf(wchv[r][j], 0.98f, fmaf(bn_[j], post, an_[j])), -rWch[r][j]);
#pragma unroll
        for (int j = 0; j < 6; ++j)
          whh[r][j] = fmaxf(fmaf(whh[r][j], 0.98f, fmaf(bh_[j], post, ah_[j])), -rWhh[r][j]);
      }
    }

    // finish own noh poll -> ohr for step t+1
    for (;;) {
      const bool ok = (ph0 != 0.f) & (ph1 != 0.f) & (ph2 != 0.f) &
                      (ph3 != 0.f) & (ph4 != 0.f) & (ph5 != 0.f);
      if (ok) break;
      ph0 = aldf(pph + 0*64); ph1 = aldf(pph + 1*64); ph2 = aldf(pph + 2*64);
      ph3 = aldf(pph + 3*64); ph4 = aldf(pph + 4*64); ph5 = aldf(pph + 5*64);
    }
    ohr[0] = ph0 - 2.f; ohr[1] = ph1 - 2.f; ohr[2] = ph2 - 2.f;
    ohr[3] = ph3 - 2.f; ohr[4] = ph4 - 2.f; ohr[5] = ph5 - 2.f;

#pragma unroll
    for (int j = 0; j < 6; ++j) ocr[j] = ncr[j];  // oc <- noc
  }

  // final output row t = NT-1 (ohr holds noh[31] from the last poll)
  if (do_out) {
#pragma unroll
    for (int m = 0; m < 4; ++m) {
      float a = 0.f;
#pragma unroll
      for (int j = 0; j < 5; ++j) a += rWo[m][j] * ohr[j];
#pragma unroll
      for (int mm = 1; mm <= 32; mm <<= 1) a += __shfl_xor(a, mm, 64);
      if (lane == 0) out[(NT-1)*NBATCH*DOUT + b*DOUT + wv*4 + m] = a;
    }
  }
}

extern "C" void kernel_launch(void* const* d_in, const int* in_sizes, int n_in,
                              void* d_out, int out_size, void* d_ws, size_t ws_size,
                              hipStream_t stream) {
  const float* x   = (const float*)d_in[0];
  const float* Rs  = (const float*)d_in[1];
  const float* Wx  = (const float*)d_in[2];
  const float* Wc  = (const float*)d_in[3];
  const float* bc  = (const float*)d_in[4];
  const float* Wch = (const float*)d_in[5];
  const float* Whh = (const float*)d_in[6];
  const float* bh  = (const float*)d_in[7];
  const float* Wo  = (const float*)d_in[8];
  const float* Wa  = (const float*)d_in[9];
  const float* ba  = (const float*)d_in[10];
  const float* kap = (const float*)d_in[11];
  float* out = (float*)d_out;

  float* comm = (float*)d_ws;  // 2*CSZ floats = 1.5 MiB
  hipMemsetAsync(comm, 0, (size_t)2 * CSZ * sizeof(float), stream);

  hipLaunchKernelGGL(hrnn, dim3(256), dim3(512), 0, stream,
                     x, Rs, Wx, Wc, bc, Wch, Whh, bh, Wo, Wa, ba, kap,
                     out, comm);
}

// Round 15
// 169.384 us; speedup vs baseline: 2.8201x; 2.8201x over previous
//
#include <hip/hip_runtime.h>

// HierarchicalRNN T=32,B=16,I=128,H=384,O=32.
// FINAL = round-6 configuration (best measured: 170 us).
// Persistent-register plastic weights; fence-free dataflow sync via
// agent-scope relaxed atomics. Wave 0 polls, LDS broadcast to 7 waves.
// gather6G issues all 6 poll loads WITHOUT intervening branches -> all 6
// MALL round trips overlap per poll round.
// Comm words self-flagging (v+2.0, sentinel 0), t-indexed buffers.
// Structural floor: 64 sequential cross-CU visibility hops x ~2.3us
// (agent-scope store->remote-load latency) ~= 147us; this kernel sits at
// ~170us. Variants tried and beaten by this one: dedicated poller waves
// (r7-r9: regalloc spills >128 VGPR), phase-specialized blocks (r10-r11:
// spill/deadlock), wave-teams (r12), split/rotated pollers (r13),
// all-wave polling (r14: fabric congestion).

#define NT 32
#define NBATCH 16
#define DI 128
#define DH 384
#define DOUT 32
#define CSZ (NT * NBATCH * DH)

__device__ __forceinline__ float retanh_f(float z) {
  z = fmaxf(z, 0.0f);
  float e = __expf(-2.0f * z);
  return (1.0f - e) / (1.0f + e);
}

__device__ __forceinline__ float aldf(const float* p) {
  return __hip_atomic_load(p, __ATOMIC_RELAXED, __HIP_MEMORY_SCOPE_AGENT);
}
__device__ __forceinline__ void pubG(float* p, float v) {
  __hip_atomic_store(p, v, __ATOMIC_RELAXED, __HIP_MEMORY_SCOPE_AGENT);
}

// Poll 6 lane-owned words. All 6 loads issued back-to-back (no branches
// between) so they overlap in flight; one combined readiness check.
__device__ __forceinline__ void gather6G(const float* src, int lane, float arr[6]) {
  const float* p = src + lane;
  float v0, v1, v2, v3, v4, v5;
  for (;;) {
    v0 = aldf(p + 0 * 64);
    v1 = aldf(p + 1 * 64);
    v2 = aldf(p + 2 * 64);
    v3 = aldf(p + 3 * 64);
    v4 = aldf(p + 4 * 64);
    v5 = aldf(p + 5 * 64);
    const bool ok = (v0 != 0.f) & (v1 != 0.f) & (v2 != 0.f) &
                    (v3 != 0.f) & (v4 != 0.f) & (v5 != 0.f);
    if (ok) break;
  }
  arr[0] = v0 - 2.f; arr[1] = v1 - 2.f; arr[2] = v2 - 2.f;
  arr[3] = v3 - 2.f; arr[4] = v4 - 2.f; arr[5] = v5 - 2.f;
}

__global__ __launch_bounds__(512, 2) void hrnn(
    const float* __restrict__ x, const float* __restrict__ Rs,
    const float* __restrict__ Wx, const float* __restrict__ Wc, const float* __restrict__ bc,
    const float* __restrict__ Wch, const float* __restrict__ Whh, const float* __restrict__ bh,
    const float* __restrict__ Wo, const float* __restrict__ Wa, const float* __restrict__ ba,
    const float* __restrict__ kap, float* __restrict__ out, float* __restrict__ comm) {
  const int tid  = threadIdx.x;
  const int lane = tid & 63;
  const int wv   = tid >> 6;
  const int bid  = blockIdx.x;
  const int b = ((bid & 7) << 1) | ((bid >> 3) & 1);
  const int k = bid >> 4;

  float* noc_buf = comm;         // [NT][NBATCH][DH]
  float* noh_buf = comm + CSZ;   // [NT][NBATCH][DH]

  __shared__ float sh_noh[DH];
  __shared__ float sh_noc[DH];

  const int og0 = k * 24 + wv * 3;
  const bool do_out = (k == 15);

  // persistent plastic weights + cached relu(W_slow) slices (all registers)
  float wxc[3][2], wcc[3][6], wchv[3][5], whh[3][6];
  float rWx[3][2], rWc[3][6], rWch[3][5], rWhh[3][6], rWa[3][5];
  float sc[3], shs[3], bcr[3], bar3[3], bhr[3];
  float ohr[6], ocr[6];
  float rWo[4][5];

#pragma unroll
  for (int r = 0; r < 3; ++r) {
    const int og = og0 + r;
#pragma unroll
    for (int j = 0; j < 2; ++j) { rWx[r][j] = fmaxf(Wx[og*DI + j*64 + lane], 0.f); wxc[r][j] = 0.f; }
#pragma unroll
    for (int j = 0; j < 6; ++j) { rWc[r][j] = fmaxf(Wc[og*DH + j*64 + lane], 0.f); wcc[r][j] = 0.f; }
#pragma unroll
    for (int j = 0; j < 5; ++j) { rWch[r][j] = fmaxf(Wch[og*DH + j*64 + lane], 0.f); wchv[r][j] = 0.f; }
#pragma unroll
    for (int j = 0; j < 6; ++j) { rWhh[r][j] = fmaxf(Whh[og*DH + j*64 + lane], 0.f); whh[r][j] = 0.f; }
#pragma unroll
    for (int j = 0; j < 5; ++j) {
      float w = fmaxf(Wa[og*DH + j*64 + lane], 0.f);
      rWa[r][j] = (j == 4 && lane >= 51) ? 0.f : w;   // attn mask: cols>=307 zero
    }
    sc[r] = 0.f; shs[r] = 0.f;
    bcr[r] = bc[og]; bar3[r] = ba[og]; bhr[r] = bh[og];
  }
  if (do_out) {
#pragma unroll
    for (int m = 0; m < 4; ++m) {
      const int o = wv * 4 + m;
#pragma unroll
      for (int j = 0; j < 5; ++j) {
        float w = fmaxf(Wo[o*DH + j*64 + lane], 0.f);
        rWo[m][j] = (j == 4 && lane >= 51) ? 0.f : w;  // h2o mask: cols>=307 zero
      }
    }
  }
#pragma unroll
  for (int j = 0; j < 6; ++j) { ohr[j] = 0.f; ocr[j] = 0.f; }
  float kp[12];
#pragma unroll
  for (int j = 0; j < 12; ++j) kp[j] = kap[j];

  // prefetch step-0 inputs
  float xp0 = x[b*DI + lane];
  float xp1 = x[b*DI + 64 + lane];
  float dtRp = 0.02f * Rs[b];

  for (int t = 0; t < NT; ++t) {
    const int toff = t * NBATCH * DH + b * DH;

    // ---- gather noh[t-1]: wave 0 polls, LDS broadcast ----
    if (t > 0) {
      if (wv == 0) {
        float tmp[6];
        gather6G(noh_buf + toff - NBATCH * DH, lane, tmp);
#pragma unroll
        for (int j = 0; j < 6; ++j) sh_noh[j * 64 + lane] = tmp[j];
      }
      __syncthreads();   // B1
#pragma unroll
      for (int j = 0; j < 6; ++j) ohr[j] = sh_noh[j * 64 + lane];
    }

    const float dtR = dtRp;
    const float x0 = xp0;
    const float x1 = xp1;
    // column sign masks (boundary col 307 = j4/lane51)
    const float oh4s = (lane < 51) ? ohr[4] : -ohr[4];
    const float oc4s = (lane < 51) ? ocr[4] : -ocr[4];
    const float inC[6] = { ocr[0], ocr[1], ocr[2], ocr[3], oc4s, -ocr[5] };

    // ---------------- phase A (cell layer) ----------------
    float nocr[3];
#pragma unroll
    for (int r = 0; r < 3; ++r) {
      const int og = og0 + r;
      const int dj = og >> 6, dl = og & 63;
      float accA = 0.f, accT = 0.f;
#pragma unroll
      for (int j = 0; j < 5; ++j) accA += rWa[r][j] * ohr[j];
      accT += (rWx[r][0] + wxc[r][0]) * x0;
      accT += (rWx[r][1] + wxc[r][1]) * x1;
#pragma unroll
      for (int j = 0; j < 6; ++j) {
        float term = (rWc[r][j] + wcc[r][j]) * inC[j];
        if (j == dj) term = (lane == dl) ? 0.f : term;  // remove_diag
        accT += term;
      }
#pragma unroll
      for (int mm = 1; mm <= 32; mm <<= 1) {
        accA += __shfl_xor(accA, mm, 64);
        accT += __shfl_xor(accT, mm, 64);
      }
      const float attn = retanh_f(accA + bar3[r]);
      const float tic = accT + bcr[r] + attn;
      sc[r] = 0.8f*sc[r] + 0.2f*tic;
      nocr[r] = retanh_f(sc[r]);
    }
    {  // coalesced publish: lanes 0..2, one 12B store per wave
      float mine = (lane == 0) ? nocr[0] : (lane == 1) ? nocr[1] : nocr[2];
      if (lane < 3) pubG(noc_buf + toff + og0 + lane, mine + 2.0f);
    }

    // --- overlapped region (hides other blocks' phase A + our poll) ---
    if (t < NT-1) {  // input prefetch
      xp0 = x[((t+1)*NBATCH + b)*DI + lane];
      xp1 = x[((t+1)*NBATCH + b)*DI + 64 + lane];
      dtRp = 0.02f * Rs[(t+1)*NBATCH + b];
    }
    if (do_out && t > 0) {  // out[t-1]
#pragma unroll
      for (int m = 0; m < 4; ++m) {
        float a = 0.f;
#pragma unroll
        for (int j = 0; j < 5; ++j) a += rWo[m][j] * ohr[j];
#pragma unroll
        for (int mm = 1; mm <= 32; mm <<= 1) a += __shfl_xor(a, mm, 64);
        if (lane == 0) out[(t-1)*NBATCH*DOUT + b*DOUT + wv*4 + m] = a;
      }
    }
    if (t < NT-1) {  // plast wxc, wcc (uses OLD oc)
      float axc[2], bxc[2];
#pragma unroll
      for (int j = 0; j < 2; ++j) {
        const float pre = (j == 0) ? x0 : x1;
        axc[j] = dtR*kp[0]*pre; bxc[j] = dtR*(kp[1] + kp[2]*pre);
      }
      float acc_[6], bcc_[6];
#pragma unroll
      for (int j = 0; j < 6; ++j) { acc_[j] = dtR*kp[3]*ocr[j]; bcc_[j] = dtR*(kp[4] + kp[5]*ocr[j]); }
#pragma unroll
      for (int r = 0; r < 3; ++r) {
        const float post = nocr[r];
#pragma unroll
        for (int j = 0; j < 2; ++j)
          wxc[r][j] = fmaxf(fmaf(wxc[r][j], 0.98f, fmaf(bxc[j], post, axc[j])), -rWx[r][j]);
#pragma unroll
        for (int j = 0; j < 6; ++j)
          wcc[r][j] = fmaxf(fmaf(wcc[r][j], 0.98f, fmaf(bcc_[j], post, acc_[j])), -rWc[r][j]);
      }
    }

    // ---- gather noc[t]: wave 0 polls, LDS broadcast ----
    if (wv == 0) {
      float tmp[6];
      gather6G(noc_buf + toff, lane, tmp);
#pragma unroll
      for (int j = 0; j < 6; ++j) sh_noc[j * 64 + lane] = tmp[j];
    }
    __syncthreads();   // B2
    float ncr[6];
#pragma unroll
    for (int j = 0; j < 6; ++j) ncr[j] = sh_noc[j * 64 + lane];

    // ---------------- phase B (hidden layer) ----------------
    const float nc4z = (lane < 51) ? ncr[4] : 0.f;
    const float inH[6] = { ohr[0], ohr[1], ohr[2], ohr[3], oh4s, -ohr[5] };
    const float inN[5] = { ncr[0], ncr[1], ncr[2], ncr[3], nc4z };
    float nohr[3];
#pragma unroll
    for (int r = 0; r < 3; ++r) {
      const int og = og0 + r;
      const int dj = og >> 6, dl = og & 63;
      float acc = 0.f;
#pragma unroll
      for (int j = 0; j < 5; ++j) acc += (rWch[r][j] + wchv[r][j]) * inN[j];
#pragma unroll
      for (int j = 0; j < 6; ++j) {
        float term = (rWhh[r][j] + whh[r][j]) * inH[j];
        if (j == dj) term = (lane == dl) ? 0.f : term;
        acc += term;
      }
#pragma unroll
      for (int mm = 1; mm <= 32; mm <<= 1) acc += __shfl_xor(acc, mm, 64);
      const float tih = acc + bhr[r];
      shs[r] = 0.8f*shs[r] + 0.2f*tih;
      nohr[r] = retanh_f(shs[r]);
    }
    {
      float mine = (lane == 0) ? nohr[0] : (lane == 1) ? nohr[1] : nohr[2];
      if (lane < 3) pubG(noh_buf + toff + og0 + lane, mine + 2.0f);
    }

    // plast wch, whh (pre: new noc / old oh; post: new noh)
    if (t < NT-1) {
      float an_[5], bn_[5];
#pragma unroll
      for (int j = 0; j < 5; ++j) { an_[j] = dtR*kp[6]*ncr[j]; bn_[j] = dtR*(kp[7] + kp[8]*ncr[j]); }
      float ah_[6], bh_[6];
#pragma unroll
      for (int j = 0; j < 6; ++j) { ah_[j] = dtR*kp[9]*ohr[j]; bh_[j] = dtR*(kp[10] + kp[11]*ohr[j]); }
#pragma unroll
      for (int r = 0; r < 3; ++r) {
        const float post = nohr[r];
#pragma unroll
        for (int j = 0; j < 5; ++j)
          wchv[r][j] = fmaxf(fmaf(wchv[r][j], 0.98f, fmaf(bn_[j], post, an_[j])), -rWch[r][j]);
#pragma unroll
        for (int j = 0; j < 6; ++j)
          whh[r][j] = fmaxf(fmaf(whh[r][j], 0.98f, fmaf(bh_[j], post, ah_[j])), -rWhh[r][j]);
      }
    }
#pragma unroll
    for (int j = 0; j < 6; ++j) ocr[j] = ncr[j];  // oc <- noc
  }

  // final output row t = NT-1
  if (do_out) {
    if (wv == 0) {
      float tmp[6];
      gather6G(noh_buf + (NT-1)*NBATCH*DH + b*DH, lane, tmp);
#pragma unroll
      for (int j = 0; j < 6; ++j) sh_noh[j * 64 + lane] = tmp[j];
    }
    __syncthreads();
    float oh2[6];
#pragma unroll
    for (int j = 0; j < 6; ++j) oh2[j] = sh_noh[j * 64 + lane];
#pragma unroll
    for (int m = 0; m < 4; ++m) {
      float a = 0.f;
#pragma unroll
      for (int j = 0; j < 5; ++j) a += rWo[m][j] * oh2[j];
#pragma unroll
      for (int mm = 1; mm <= 32; mm <<= 1) a += __shfl_xor(a, mm, 64);
      if (lane == 0) out[(NT-1)*NBATCH*DOUT + b*DOUT + wv*4 + m] = a;
    }
  }
}

extern "C" void kernel_launch(void* const* d_in, const int* in_sizes, int n_in,
                              void* d_out, int out_size, void* d_ws, size_t ws_size,
                              hipStream_t stream) {
  const float* x   = (const float*)d_in[0];
  const float* Rs  = (const float*)d_in[1];
  const float* Wx  = (const float*)d_in[2];
  const float* Wc  = (const float*)d_in[3];
  const float* bc  = (const float*)d_in[4];
  const float* Wch = (const float*)d_in[5];
  const float* Whh = (const float*)d_in[6];
  const float* bh  = (const float*)d_in[7];
  const float* Wo  = (const float*)d_in[8];
  const float* Wa  = (const float*)d_in[9];
  const float* ba  = (const float*)d_in[10];
  const float* kap = (const float*)d_in[11];
  float* out = (float*)d_out;

  float* comm = (float*)d_ws;  // 2*CSZ floats = 1.5 MiB
  hipMemsetAsync(comm, 0, (size_t)2 * CSZ * sizeof(float), stream);

  hipLaunchKernelGGL(hrnn, dim3(256), dim3(512), 0, stream,
                     x, Rs, Wx, Wc, bc, Wch, Whh, bh, Wo, Wa, ba, kap,
                     out, comm);
}